// Round 4
// baseline (837.095 us; speedup 1.0000x reference)
//
#include <hip/hip_runtime.h>

#define NB   8192
#define NA   32
#define DIN  8
#define HID  64
#define DOUT 8

__device__ __forceinline__ float silu_f(float x) {
    return x / (1.0f + __expf(-x));
}

__global__ __launch_bounds__(256) void attn_pre_kernel(
    const float* __restrict__ x,      // (NB, NA, DIN)
    const float* __restrict__ lap,    // (NB, NA, 1)
    const float* __restrict__ W_in,   // (HID, DIN)
    const float* __restrict__ b_in,   // (HID)
    const float* __restrict__ Aq,     // (HID, HID)
    const float* __restrict__ Ak,     // (HID, HID)
    const float* __restrict__ Av,     // (HID, HID)
    const float* __restrict__ W_out,  // (DOUT, HID)
    const float* __restrict__ b_out,  // (DOUT)
    float* __restrict__ out)          // (NB, DOUT)
{
    __shared__ __align__(16) float xs[NA][DIN];     // reused as ys[NA][DOUT] at the end
    __shared__ float laps[NA];
    __shared__ __align__(16) float hs[NA][68];      // h[n][i]; reused as attn[n][i]
    __shared__ __align__(16) float wT[HID][68];     // staged W^T; reused as At[j][i] (scores/softmax)
    __shared__ __align__(16) float Qs[HID][36];     // Q[i][n]
    __shared__ __align__(16) float Ks[NA][68];      // K[n][j]
    __shared__ __align__(16) float Vt[NA][68];      // V^T: Vt[n][j] = V[j][n]

    float (*At)[68]    = wT;   // alias: scores transposed, At[j][i] = S[i][j]
    float (*attns)[68] = hs;   // alias
    float (*ys)[DIN]   = xs;   // alias (NA*DOUT == NA*DIN == 256 floats)

    const int t    = threadIdx.x;
    const int lane = t & 63;
    const int w    = t >> 6;
    const int b    = blockIdx.x;

    // ---- Phase 0: load x, laplacian ----
    xs[t >> 3][t & 7] = x[b * (NA * DIN) + t];
    if (t < NA) laps[t] = lap[b * NA + t];
    __syncthreads();

    // ---- Phase A: h[n][i] = silu(x @ W_in^T + b_in) * lap ----
    {
        float wr[DIN];
        #pragma unroll
        for (int j = 0; j < DIN; ++j) wr[j] = W_in[lane * DIN + j];
        const float bb = b_in[lane];
        #pragma unroll
        for (int k = 0; k < 8; ++k) {
            const int n = w + 4 * k;
            float acc = bb;
            #pragma unroll
            for (int j = 0; j < DIN; ++j) acc += xs[n][j] * wr[j];
            hs[n][lane] = silu_f(acc) * laps[n];
        }
    }
    __syncthreads();

    // ---- stage helper: wT[j][i] = M[i][j] (coalesced global read) ----
    auto stage = [&](const float* __restrict__ M) {
        #pragma unroll
        for (int r = 0; r < 4; ++r) {
            const int f = (t + 256 * r) * 4;   // flat float index into 64x64
            const float4 v = *(const float4*)(M + f);
            const int i = f >> 6;
            const int j = f & 63;
            wT[j + 0][i] = v.x;
            wT[j + 1][i] = v.y;
            wT[j + 2][i] = v.z;
            wT[j + 3][i] = v.w;
        }
    };

    // ---- gemm vs h: out[i][n] = silu(sum_j M[i][j] * h[n][j]) ----
    auto gemm_h = [&](int mode) {
        float acc[8] = {0.f, 0.f, 0.f, 0.f, 0.f, 0.f, 0.f, 0.f};
        for (int jc = 0; jc < 16; ++jc) {
            const float w0 = wT[jc * 4 + 0][lane];
            const float w1 = wT[jc * 4 + 1][lane];
            const float w2 = wT[jc * 4 + 2][lane];
            const float w3 = wT[jc * 4 + 3][lane];
            #pragma unroll
            for (int k = 0; k < 8; ++k) {
                const float4 hv = *(const float4*)&hs[w * 8 + k][jc * 4];
                acc[k] += w0 * hv.x + w1 * hv.y + w2 * hv.z + w3 * hv.w;
            }
        }
        #pragma unroll
        for (int k = 0; k < 8; ++k) {
            const float val = silu_f(acc[k]);
            const int n = w * 8 + k;
            if (mode == 0)      Qs[lane][n] = val;  // Q[i][n]
            else if (mode == 1) Ks[n][lane] = val;  // K[n][j]
            else                Vt[n][lane] = val;  // V^T[n][j]
        }
    };

    stage(Aq); __syncthreads();
    gemm_h(0); __syncthreads();
    stage(Ak); __syncthreads();
    gemm_h(1); __syncthreads();
    stage(Av); __syncthreads();
    gemm_h(2); __syncthreads();

    // ---- Phase C+D: S[i][j] = sum_n Q[i][n] K[n][j]; softmax over j (across lanes) ----
    {
        float acc[16];
        #pragma unroll
        for (int r = 0; r < 16; ++r) acc[r] = 0.f;
        for (int nc = 0; nc < 8; ++nc) {
            const float k0 = Ks[nc * 4 + 0][lane];
            const float k1 = Ks[nc * 4 + 1][lane];
            const float k2 = Ks[nc * 4 + 2][lane];
            const float k3 = Ks[nc * 4 + 3][lane];
            #pragma unroll
            for (int r = 0; r < 16; ++r) {
                const float4 qv = *(const float4*)&Qs[w * 16 + r][nc * 4];
                acc[r] += qv.x * k0 + qv.y * k1 + qv.z * k2 + qv.w * k3;
            }
        }
        // softmax along j == along lanes; row i = w*16 + r
        #pragma unroll
        for (int r = 0; r < 16; ++r) {
            const float v = acc[r];
            float m = v;
            #pragma unroll
            for (int s = 32; s; s >>= 1) m = fmaxf(m, __shfl_xor(m, s, 64));
            const float e = __expf(v - m);
            float sum = e;
            #pragma unroll
            for (int s = 32; s; s >>= 1) sum += __shfl_xor(sum, s, 64);
            At[lane][w * 16 + r] = e / sum;   // At[j][i] = A[i][j]
        }
    }
    __syncthreads();

    // ---- Phase E: attn[n][i] = silu(sum_j A[i][j] V[j][n]) ----
    {
        float acc[8] = {0.f, 0.f, 0.f, 0.f, 0.f, 0.f, 0.f, 0.f};
        for (int jc = 0; jc < 16; ++jc) {
            const float a0 = At[jc * 4 + 0][lane];
            const float a1 = At[jc * 4 + 1][lane];
            const float a2 = At[jc * 4 + 2][lane];
            const float a3 = At[jc * 4 + 3][lane];
            #pragma unroll
            for (int k = 0; k < 8; ++k) {
                const float4 vv = *(const float4*)&Vt[w * 8 + k][jc * 4];
                acc[k] += a0 * vv.x + a1 * vv.y + a2 * vv.z + a3 * vv.w;
            }
        }
        #pragma unroll
        for (int k = 0; k < 8; ++k)
            attns[w * 8 + k][lane] = silu_f(acc[k]);
    }
    __syncthreads();

    // ---- Phase F: y[n][o] = silu(attn @ W_out^T + b_out) * lap; mean over n ----
    {
        const int n = t >> 3;
        const int o = t & 7;
        float acc = b_out[o];
        #pragma unroll
        for (int ic = 0; ic < 16; ++ic) {
            const float4 av = *(const float4*)&attns[n][ic * 4];
            const float4 wv = *(const float4*)&W_out[o * HID + ic * 4];
            acc += av.x * wv.x + av.y * wv.y + av.z * wv.z + av.w * wv.w;
        }
        ys[n][o] = silu_f(acc) * laps[n];
    }
    __syncthreads();
    if (t < DOUT) {
        float s = 0.f;
        #pragma unroll
        for (int n = 0; n < NA; ++n) s += ys[n][t];
        out[b * DOUT + t] = s * (1.0f / NA);
    }
}

extern "C" void kernel_launch(void* const* d_in, const int* in_sizes, int n_in,
                              void* d_out, int out_size, void* d_ws, size_t ws_size,
                              hipStream_t stream) {
    const float* x     = (const float*)d_in[0];
    const float* lap   = (const float*)d_in[1];
    const float* W_in  = (const float*)d_in[2];
    const float* b_in  = (const float*)d_in[3];
    const float* Aq    = (const float*)d_in[4];
    const float* Ak    = (const float*)d_in[5];
    const float* Av    = (const float*)d_in[6];
    const float* W_out = (const float*)d_in[7];
    const float* b_out = (const float*)d_in[8];
    attn_pre_kernel<<<NB, 256, 0, stream>>>(x, lap, W_in, b_in, Aq, Ak, Av,
                                            W_out, b_out, (float*)d_out);
}

// Round 5
// 62.393 us; speedup vs baseline: 13.4165x; 13.4165x over previous
//
#include <hip/hip_runtime.h>

#define NB   8192
#define NA   32
#define DIN  8
#define HID  64
#define DOUT 8

typedef float     v4f __attribute__((ext_vector_type(4)));
typedef _Float16  v4h __attribute__((ext_vector_type(4)));

__device__ __forceinline__ float silu_f(float x) {
    // x * sigmoid(x); __fdividef -> v_rcp+mul. Large |x| limits are correct.
    return __fdividef(x, 1.0f + __expf(-x));
}

__device__ __forceinline__ v4h cvt4(v4f a) {   // RNE converts (v_cvt_f16_f32)
    v4h r;
    r[0] = (_Float16)a[0]; r[1] = (_Float16)a[1];
    r[2] = (_Float16)a[2]; r[3] = (_Float16)a[3];
    return r;
}

__device__ __forceinline__ v4h silu_cvt4(v4f a) {
    v4f s;
    s[0] = silu_f(a[0]); s[1] = silu_f(a[1]);
    s[2] = silu_f(a[2]); s[3] = silu_f(a[3]);
    return cvt4(s);
}

#define MFMA16(A, B, C) __builtin_amdgcn_mfma_f32_16x16x16f16((A), (B), (C), 0, 0, 0)

// One wave processes one batch item entirely in MFMA fragments.
// 16x16x16 f16 chaining: C-frag (col = l&15, row = 4*(l>>4)+r) of stage k
// IS the A/B-operand frag (m or n = l&15, k = 4*(l>>4)+r) of stage k+1.
__global__ __launch_bounds__(256, 3) void attn_mfma_kernel(
    const float* __restrict__ x,      // (NB, NA, DIN)
    const float* __restrict__ lap,    // (NB, NA)
    const float* __restrict__ W_in,   // (HID, DIN)
    const float* __restrict__ b_in,   // (HID)
    const float* __restrict__ Aq,     // (HID, HID)
    const float* __restrict__ Ak,     // (HID, HID)
    const float* __restrict__ Av,     // (HID, HID)
    const float* __restrict__ W_out,  // (DOUT, HID)
    const float* __restrict__ b_out,  // (DOUT)
    float* __restrict__ out)          // (NB, DOUT)
{
    // Frag-ordered f16 weights: [mat][frag = it*4+ks][lane][4]  (24 KB)
    __shared__ _Float16 wlds[3][16][64][4];
    // Per-wave h frags: [wave][frag = nt*4+ks][lane][4]         (16 KB)
    __shared__ _Float16 hlds[4][8][64][4];

    const int t  = threadIdx.x;
    const int l  = t & 63;
    const int w  = t >> 6;
    const int lm = l & 15;
    const int lg = l >> 4;

    // ---- stage Aq/Ak/Av into LDS as f16 B/A-frags (once per block) ----
    {
        const float* mats[3] = {Aq, Ak, Av};
        #pragma unroll
        for (int m = 0; m < 3; ++m) {
            #pragma unroll
            for (int f = 0; f < 4; ++f) {
                const int fid = w * 4 + f;          // wave w stages frags 4w..4w+3
                const int it = fid >> 2, ks = fid & 3;
                v4f v = *(const v4f*)(mats[m] + (lm + 16 * it) * 64 + 16 * ks + 4 * lg);
                *(v4h*)&wlds[m][fid][l][0] = cvt4(v);
            }
        }
    }

    // ---- persistent register frags ----
    v4h zh = {};
    v4f zf = {};
    v4h winf[4];                                   // W_in^T B-frags (k=d, col j)
    #pragma unroll
    for (int jt = 0; jt < 4; ++jt)
        winf[jt] = (lg < 2) ? cvt4(*(const v4f*)(W_in + (lm + 16 * jt) * 8 + 4 * lg)) : zh;
    v4h woutf[4];                                  // W_out^T B-frags (k=i, col o<8)
    #pragma unroll
    for (int ks = 0; ks < 4; ++ks)
        woutf[ks] = (lm < 8) ? cvt4(*(const v4f*)(W_out + lm * 64 + 16 * ks + 4 * lg)) : zh;
    float binf[4];
    #pragma unroll
    for (int jt = 0; jt < 4; ++jt) binf[jt] = b_in[lm + 16 * jt];
    const float boutf = (lm < 8) ? b_out[lm] : 0.0f;

    __syncthreads();   // the only block barrier

    // ---- item loop: wave gw handles items gw, gw+3072, ... ----
    for (int b = blockIdx.x * 4 + w; b < NB; b += 3072) {
        // laplacian at rows n = 4*lg + r + 16*nt  (reused in h stage and epilogue)
        v4f lapv[2];
        lapv[0] = *(const v4f*)(lap + b * 32 + 4 * lg);
        lapv[1] = *(const v4f*)(lap + b * 32 + 16 + 4 * lg);

        // x A-frags: m=n=lm+16nt, k=d=4lg+r (d<8 valid; others zero)
        v4h xf[2];
        #pragma unroll
        for (int nt = 0; nt < 2; ++nt)
            xf[nt] = (lg < 2) ? cvt4(*(const v4f*)(x + b * 256 + (lm + 16 * nt) * 8 + 4 * lg)) : zh;

        // ---- h = silu(x @ W_in^T + b_in) * lap ; write C-frags as A-frags to LDS ----
        #pragma unroll
        for (int nt = 0; nt < 2; ++nt) {
            #pragma unroll
            for (int jt = 0; jt < 4; ++jt) {
                v4f hc = MFMA16(xf[nt], winf[jt], zf);   // C: col j=lm+16jt, row n=4lg+r+16nt
                #pragma unroll
                for (int r = 0; r < 4; ++r) {
                    float hv = silu_f(hc[r] + binf[jt]) * lapv[nt][r];
                    const int lr = (4 * lg + r) | ((lm >> 2) << 4);  // reader lane
                    hlds[w][nt * 4 + jt][lr][lm & 3] = (_Float16)hv;
                }
            }
        }
        __builtin_amdgcn_s_waitcnt(0);  // drain ds writes before cross-lane reads (same wave)

        // h A/B-frags: value h[n=lm+16nt][j=4lg+r+16ks]
        v4h hf[2][4];
        #pragma unroll
        for (int nt = 0; nt < 2; ++nt)
            #pragma unroll
            for (int ks = 0; ks < 4; ++ks)
                hf[nt][ks] = *(v4h*)&hlds[w][nt * 4 + ks][l][0];

        // ---- QT[n][i] = h @ Aq^T  (then silu -> Q[n][i]) ----
        v4h qf[2][4];                     // [nt][it]
        {
            v4f acc[2][4] = {};
            #pragma unroll
            for (int it = 0; it < 4; ++it)
                #pragma unroll
                for (int ks = 0; ks < 4; ++ks) {
                    v4h bw = *(v4h*)&wlds[0][it * 4 + ks][l][0];
                    #pragma unroll
                    for (int nt = 0; nt < 2; ++nt)
                        acc[nt][it] = MFMA16(hf[nt][ks], bw, acc[nt][it]);
                }
            #pragma unroll
            for (int nt = 0; nt < 2; ++nt)
                #pragma unroll
                for (int it = 0; it < 4; ++it) qf[nt][it] = silu_cvt4(acc[nt][it]);
        }
        // ---- KT[n][i] = h @ Ak^T ----
        v4h kf[2][4];
        {
            v4f acc[2][4] = {};
            #pragma unroll
            for (int it = 0; it < 4; ++it)
                #pragma unroll
                for (int ks = 0; ks < 4; ++ks) {
                    v4h bw = *(v4h*)&wlds[1][it * 4 + ks][l][0];
                    #pragma unroll
                    for (int nt = 0; nt < 2; ++nt)
                        acc[nt][it] = MFMA16(hf[nt][ks], bw, acc[nt][it]);
                }
            #pragma unroll
            for (int nt = 0; nt < 2; ++nt)
                #pragma unroll
                for (int it = 0; it < 4; ++it) kf[nt][it] = silu_cvt4(acc[nt][it]);
        }
        // ---- VV[i][n] = Av @ h^T  (then silu -> V[i][n]) ----
        v4h vf[4][2];                     // [it][nt]
        {
            v4f acc[4][2] = {};
            #pragma unroll
            for (int it = 0; it < 4; ++it)
                #pragma unroll
                for (int ks = 0; ks < 4; ++ks) {
                    v4h aw = *(v4h*)&wlds[2][it * 4 + ks][l][0];
                    #pragma unroll
                    for (int nt = 0; nt < 2; ++nt)
                        acc[it][nt] = MFMA16(aw, hf[nt][ks], acc[it][nt]);
                }
            #pragma unroll
            for (int it = 0; it < 4; ++it)
                #pragma unroll
                for (int nt = 0; nt < 2; ++nt) vf[it][nt] = silu_cvt4(acc[it][nt]);
        }

        // ---- S^T[j][i] = K^T(j,n) @ Q(n,i): A=kf[ns][jt], B=qf[ns][it] ----
        v4f st[4][4] = {};                // [jt][it]: row j=4lg+r+16jt, col i=lm+16it
        #pragma unroll
        for (int jt = 0; jt < 4; ++jt)
            #pragma unroll
            for (int it = 0; it < 4; ++it)
                #pragma unroll
                for (int ns = 0; ns < 2; ++ns)
                    st[jt][it] = MFMA16(kf[ns][jt], qf[ns][it], st[jt][it]);

        // ---- softmax over j (regs + lane-groups), P -> PV A-frags ----
        v4h pf[4][4];                     // [it][jt]
        #pragma unroll
        for (int it = 0; it < 4; ++it) {
            float mx = st[0][it][0];
            #pragma unroll
            for (int jt = 0; jt < 4; ++jt)
                #pragma unroll
                for (int r = 0; r < 4; ++r) mx = fmaxf(mx, st[jt][it][r]);
            mx = fmaxf(mx, __shfl_xor(mx, 16, 64));
            mx = fmaxf(mx, __shfl_xor(mx, 32, 64));
            float sum = 0.0f;
            #pragma unroll
            for (int jt = 0; jt < 4; ++jt)
                #pragma unroll
                for (int r = 0; r < 4; ++r) {
                    float e = __expf(st[jt][it][r] - mx);
                    st[jt][it][r] = e;
                    sum += e;
                }
            sum += __shfl_xor(sum, 16, 64);
            sum += __shfl_xor(sum, 32, 64);
            const float inv = __fdividef(1.0f, sum);
            #pragma unroll
            for (int jt = 0; jt < 4; ++jt) {
                v4f p = st[jt][it] * inv;
                pf[it][jt] = cvt4(p);
            }
        }

        // ---- attnM[i][n] = P(i,j) @ V(j,n): A=pf[it][js], B=vf[js][nt] ----
        v4f pv[4][2] = {};                // [it][nt]
        #pragma unroll
        for (int it = 0; it < 4; ++it)
            #pragma unroll
            for (int js = 0; js < 4; ++js)
                #pragma unroll
                for (int nt = 0; nt < 2; ++nt)
                    pv[it][nt] = MFMA16(pf[it][js], vf[js][nt], pv[it][nt]);

        // ---- y = silu(attn @ W_out^T + b_out) * lap ; mean over n ----
        v4f ya[2] = {};                   // [nt]: col o=lm(<8), row n=4lg+r+16nt
        #pragma unroll
        for (int nt = 0; nt < 2; ++nt)
            #pragma unroll
            for (int is = 0; is < 4; ++is)
                ya[nt] = MFMA16(silu_cvt4(pv[is][nt]), woutf[is], ya[nt]);

        float acc = 0.0f;
        #pragma unroll
        for (int nt = 0; nt < 2; ++nt)
            #pragma unroll
            for (int r = 0; r < 4; ++r)
                acc += silu_f(ya[nt][r] + boutf) * lapv[nt][r];
        acc += __shfl_xor(acc, 16, 64);
        acc += __shfl_xor(acc, 32, 64);
        if (l < 8) out[b * DOUT + l] = acc * (1.0f / NA);
    }
}

extern "C" void kernel_launch(void* const* d_in, const int* in_sizes, int n_in,
                              void* d_out, int out_size, void* d_ws, size_t ws_size,
                              hipStream_t stream) {
    const float* x     = (const float*)d_in[0];
    const float* lap   = (const float*)d_in[1];
    const float* W_in  = (const float*)d_in[2];
    const float* b_in  = (const float*)d_in[3];
    const float* Aq    = (const float*)d_in[4];
    const float* Ak    = (const float*)d_in[5];
    const float* Av    = (const float*)d_in[6];
    const float* W_out = (const float*)d_in[7];
    const float* b_out = (const float*)d_in[8];
    attn_mfma_kernel<<<768, 256, 0, stream>>>(x, lap, W_in, b_in, Aq, Ak, Av,
                                              W_out, b_out, (float*)d_out);
}